// Round 2
// baseline (568.468 us; speedup 1.0000x reference)
//
#include <hip/hip_runtime.h>

#define NPROT 12288
#define NMOL  6144
#define HID   256
#define NB    32

typedef __attribute__((ext_vector_type(4))) float f32x4;
typedef __attribute__((ext_vector_type(8))) short bf16x8;
typedef unsigned short u16;
typedef unsigned int   u32;

__device__ __forceinline__ float b2f(u16 u){
  union { u32 i; float f; } v; v.i = ((u32)u) << 16; return v.f;
}
__device__ __forceinline__ u16 f2b(float f){
  union { float fl; u32 i; } v; v.fl = f;
  u32 i = v.i;
  return (u16)((i + 0x7FFFu + ((i >> 16) & 1u)) >> 16);  // RNE
}

// Load 8 consecutive elements (element offset `off`) as a bf16 MFMA fragment,
// from either an f32 array (convert) or a bf16 array, per wave-uniform flag.
__device__ __forceinline__ bf16x8 ld8(const void* base, size_t off, int f32f){
  if (f32f){
    const float* p = (const float*)base + off;
    f32x4 a = *(const f32x4*)p;
    f32x4 b = *(const f32x4*)(p + 4);
    bf16x8 r;
    r[0]=(short)f2b(a[0]); r[1]=(short)f2b(a[1]); r[2]=(short)f2b(a[2]); r[3]=(short)f2b(a[3]);
    r[4]=(short)f2b(b[0]); r[5]=(short)f2b(b[1]); r[6]=(short)f2b(b[2]); r[7]=(short)f2b(b[3]);
    return r;
  }
  return *(const bf16x8*)((const u16*)base + off);
}

// ---------------------------------------------------------------------------
// Stage 1: per-batch ranges from the sorted batch arrays + dtype probe.
// rg[0..31]=prot start, [32..63]=prot end, [64..95]=mol start, [96..127]=mol end
// rg[128] = 1 if inputs are float32, 0 if bf16.
// Probe: low half-words of f32 data are uniform random -> ~52% have bf16
// exponent field >= 0x7B; genuine bf16 U(-1/16,1/16) weights have ~none.
// ---------------------------------------------------------------------------
__global__ void ranges_kernel(const int* __restrict__ pb, const int* __restrict__ mb,
                              const u32* __restrict__ wq_raw, int* __restrict__ rg){
  int t = threadIdx.x;
  if (t < 132) rg[t] = 0;
  __syncthreads();
  for (int i = t; i < NPROT; i += 256){
    int b = pb[i];
    if (i == 0 || pb[i-1] != b) rg[b] = i;
    if (i == NPROT-1 || pb[i+1] != b) rg[32+b] = i+1;
  }
  for (int i = t; i < NMOL; i += 256){
    int b = mb[i];
    if (i == 0 || mb[i-1] != b) rg[64+b] = i;
    if (i == NMOL-1 || mb[i+1] != b) rg[96+b] = i+1;
  }
  if (t == 0){
    int cnt = 0;
    for (int i = 0; i < 256; i++){
      u32 lo = wq_raw[i] & 0xFFFFu;
      if (((lo >> 7) & 0xFFu) >= 0x7Bu) cnt++;
    }
    rg[128] = (cnt >= 32) ? 1 : 0;
  }
}

// ---------------------------------------------------------------------------
// Stage 2: projections. out[i][j] = sum_k x[i][k]*W[j][k] + b[j]  (x @ W.T + b)
// blockIdx.z: 0=Q (prot), 1=K (mol), 2=V (mol, stored TRANSPOSED as Vt[h][mol]).
// Wave computes a 16x64 tile. C/D layout: col=lane&15, row=(lane>>4)*4+reg.
// Internal Q/K/Vt are always bf16.
// ---------------------------------------------------------------------------
__global__ __launch_bounds__(256) void proj_kernel(
    const void* __restrict__ prot, const void* __restrict__ mol,
    const void* __restrict__ Wq, const void* __restrict__ bq,
    const void* __restrict__ Wk, const void* __restrict__ bk,
    const void* __restrict__ Wv, const void* __restrict__ bv,
    const int* __restrict__ rg,
    u16* __restrict__ Q, u16* __restrict__ K, u16* __restrict__ Vt)
{
  __shared__ u16 tlds[4][64][18];   // V transpose staging (pad vs bank conflicts)
  int f32f = rg[128];
  int proj = blockIdx.z;
  const void *X, *W, *bias;
  int nrows;
  if (proj == 0)      { X = prot; W = Wq; bias = bq; nrows = NPROT; }
  else if (proj == 1) { X = mol;  W = Wk; bias = bk; nrows = NMOL;  }
  else                { X = mol;  W = Wv; bias = bv; nrows = NMOL;  }
  if ((int)blockIdx.x * 64 >= nrows) return;   // block-uniform (64 | nrows)

  int wave = threadIdx.x >> 6, lane = threadIdx.x & 63;
  int m = lane & 15, q = lane >> 4;
  int rowbase = blockIdx.x * 64 + wave * 16;
  int colbase = blockIdx.y * 64;

  size_t aoff = (size_t)(rowbase + m) * HID;
  f32x4 acc[4] = {};
  for (int k0 = 0; k0 < HID; k0 += 32){
    bf16x8 a = ld8(X, aoff + k0 + q*8, f32f);
    #pragma unroll
    for (int ct = 0; ct < 4; ct++){
      bf16x8 b = ld8(W, (size_t)(colbase + ct*16 + m) * HID + k0 + q*8, f32f);
      acc[ct] = __builtin_amdgcn_mfma_f32_16x16x32_bf16(a, b, acc[ct], 0, 0, 0);
    }
  }

  if (proj < 2){
    u16* O = (proj == 0) ? Q : K;
    #pragma unroll
    for (int ct = 0; ct < 4; ct++){
      int col = colbase + ct*16 + m;
      float bb = f32f ? ((const float*)bias)[col] : b2f(((const u16*)bias)[col]);
      #pragma unroll
      for (int r = 0; r < 4; r++){
        int row = rowbase + q*4 + r;
        O[(size_t)row * HID + col] = f2b(acc[ct][r] + bb);
      }
    }
  } else {
    #pragma unroll
    for (int ct = 0; ct < 4; ct++){
      int lc = ct*16 + m;
      int col = colbase + lc;
      float bb = f32f ? ((const float*)bias)[col] : b2f(((const u16*)bias)[col]);
      #pragma unroll
      for (int r = 0; r < 4; r++)
        tlds[wave][lc][q*4 + r] = f2b(acc[ct][r] + bb);
    }
    __syncthreads();
    int col = colbase + lane;          // 64 distinct Vt rows per wave
    u32 packed[8];
    #pragma unroll
    for (int i = 0; i < 8; i++){
      u16 lo = tlds[wave][lane][2*i];
      u16 hi = tlds[wave][lane][2*i+1];
      packed[i] = (u32)lo | ((u32)hi << 16);
    }
    u16* dst = Vt + (size_t)col * NMOL + rowbase;   // 32B-aligned
    uint4 v0 = {packed[0], packed[1], packed[2], packed[3]};
    uint4 v1 = {packed[4], packed[5], packed[6], packed[7]};
    *(uint4*)dst = v0;
    *(uint4*)(dst + 8) = v1;
  }
}

// ---------------------------------------------------------------------------
// Stage 3: block-diagonal attention, fused with attn zero-fill.
// One wave owns 16 prot rows: zero-fills cols outside the batch's (32-aligned)
// block range, 2-pass online softmax over the block (MFMA QK^T recompute),
// writes P into attn and accumulates O = P @ V via MFMA against Vt.
// ---------------------------------------------------------------------------
__global__ __launch_bounds__(256) void attn_kernel(
    const int* __restrict__ rg, const u16* __restrict__ Q, const u16* __restrict__ K,
    const u16* __restrict__ Vt, void* __restrict__ dout)
{
  __shared__ u16 plds[4][16][48];   // per-wave P tile: 16 rows x 32 cols (padded)
  const float scale = 0.0625f;      // 1/sqrt(256)
  int f32f = rg[128];
  int b = blockIdx.y;
  int ps = rg[b], pe = rg[32+b], ms = rg[64+b], me = rg[96+b];
  int Np = pe - ps, Nm = me - ms;
  if (Np <= 0) return;

  int wave = threadIdx.x >> 6, lane = threadIdx.x & 63;
  int m = lane & 15, q = lane >> 4;
  float* outf  = (float*)dout;
  u16*   outh  = (u16*)dout;
  float* attnf = (float*)dout + (size_t)NPROT * HID;
  u16*   attnh = (u16*)dout   + (size_t)NPROT * HID;
  int ntiles = (Np + 15) >> 4;

  int bs, ce;                       // 32-aligned block col range written by pass 2
  if (Nm > 0){ bs = ms & ~31; ce = bs + ((me - bs + 31) & ~31); }
  else       { bs = 0; ce = 0; }

  for (int tile = blockIdx.x * 4 + wave; tile < ntiles; tile += gridDim.x * 4){
    int row0 = ps + tile * 16;

    // ---- zero-fill cols outside [bs, ce) for rows row0..row0+15 ----
    if (f32f){
      for (int cs = 0; cs < NMOL; cs += 64){
        int col = cs + m*4;
        if (col < bs || col >= ce){
          f32x4 z = {0.f, 0.f, 0.f, 0.f};
          #pragma unroll
          for (int rr = 0; rr < 4; rr++){
            int row = row0 + q*4 + rr;
            if (row < pe) *(f32x4*)(attnf + (size_t)row * NMOL + col) = z;
          }
        }
      }
    } else {
      for (int cs = 0; cs < NMOL; cs += 128){
        int col = cs + m*8;
        if (col < bs || col >= ce){
          uint4 z = {0u, 0u, 0u, 0u};
          #pragma unroll
          for (int rr = 0; rr < 4; rr++){
            int row = row0 + q*4 + rr;
            if (row < pe) *(uint4*)(attnh + (size_t)row * NMOL + col) = z;
          }
        }
      }
    }

    int qr = min(row0 + m, NPROT - 1);
    const u16* qrow = Q + (size_t)qr * HID;
    bf16x8 qf[8];
    #pragma unroll
    for (int kk = 0; kk < 8; kk++)
      qf[kk] = *(const bf16x8*)(qrow + kk*32 + q*8);

    float mx[4] = {-1e30f, -1e30f, -1e30f, -1e30f};
    float sm[4] = {0.f, 0.f, 0.f, 0.f};

    if (Nm > 0){
      // ---- pass 1: row max + online sum ----
      for (int j0 = (ms & ~15); j0 < me; j0 += 16){
        int col = j0 + m;
        bool valid = (col >= ms) && (col < me);
        const u16* krow = K + (size_t)min(col, NMOL-1) * HID;
        f32x4 s = {0.f, 0.f, 0.f, 0.f};
        #pragma unroll
        for (int kk = 0; kk < 8; kk++){
          bf16x8 kb = *(const bf16x8*)(krow + kk*32 + q*8);
          s = __builtin_amdgcn_mfma_f32_16x16x32_bf16(qf[kk], kb, s, 0, 0, 0);
        }
        float sv[4], cm[4];
        #pragma unroll
        for (int r = 0; r < 4; r++){
          sv[r] = valid ? s[r] * scale : -1e30f;
          cm[r] = sv[r];
        }
        #pragma unroll
        for (int d = 1; d < 16; d <<= 1)
          #pragma unroll
          for (int r = 0; r < 4; r++)
            cm[r] = fmaxf(cm[r], __shfl_xor(cm[r], d, 16));
        float e[4];
        #pragma unroll
        for (int r = 0; r < 4; r++){
          float mn = fmaxf(mx[r], cm[r]);
          float corr = __expf(mx[r] - mn);
          e[r] = __expf(sv[r] - mn);
          mx[r] = mn;
          sm[r] = sm[r] * corr;
        }
        #pragma unroll
        for (int d = 1; d < 16; d <<= 1)
          #pragma unroll
          for (int r = 0; r < 4; r++)
            e[r] += __shfl_xor(e[r], d, 16);
        #pragma unroll
        for (int r = 0; r < 4; r++) sm[r] += e[r];
      }
    }
    float inv[4];
    #pragma unroll
    for (int r = 0; r < 4; r++) inv[r] = (sm[r] > 0.f) ? (1.f / sm[r]) : 0.f;

    f32x4 oacc[16] = {};
    if (Nm > 0){
      // ---- pass 2: P stores (all cols in [bs,ce)) + PV ----
      for (int j0 = bs; j0 < me; j0 += 32){
        #pragma unroll
        for (int sub = 0; sub < 2; sub++){
          int col = j0 + sub*16 + m;
          bool valid = (col >= ms) && (col < me);
          const u16* krow = K + (size_t)min(col, NMOL-1) * HID;
          f32x4 s = {0.f, 0.f, 0.f, 0.f};
          #pragma unroll
          for (int kk = 0; kk < 8; kk++){
            bf16x8 kb = *(const bf16x8*)(krow + kk*32 + q*8);
            s = __builtin_amdgcn_mfma_f32_16x16x32_bf16(qf[kk], kb, s, 0, 0, 0);
          }
          #pragma unroll
          for (int r = 0; r < 4; r++){
            float pv = valid ? __expf(s[r]*scale - mx[r]) * inv[r] : 0.f;
            u16 pb16 = f2b(pv);
            plds[wave][q*4 + r][sub*16 + m] = pb16;
            int row = row0 + q*4 + r;
            if (row < pe){
              if (f32f) attnf[(size_t)row * NMOL + col] = pv;
              else      attnh[(size_t)row * NMOL + col] = pb16;
            }
          }
        }
        // PV: A = P tile from LDS (A[m][k]), B = Vt rows (B[k][n]=V[j0+k][n])
        bf16x8 a = *(const bf16x8*)(&plds[wave][m][q*8]);
        int kbase = j0 + q*8;                    // <= NMOL-8, 16B aligned
        #pragma unroll
        for (int ct = 0; ct < 16; ct++){
          bf16x8 vb = *(const bf16x8*)(Vt + (size_t)(ct*16 + m) * NMOL + kbase);
          oacc[ct] = __builtin_amdgcn_mfma_f32_16x16x32_bf16(a, vb, oacc[ct], 0, 0, 0);
        }
      }
    }
    // ---- store O (zeros if Nm==0, matching row_any handling) ----
    #pragma unroll
    for (int ct = 0; ct < 16; ct++){
      int colh = ct*16 + m;
      #pragma unroll
      for (int r = 0; r < 4; r++){
        int row = row0 + q*4 + r;
        if (row < pe){
          if (f32f) outf[(size_t)row * HID + colh] = oacc[ct][r];
          else      outh[(size_t)row * HID + colh] = f2b(oacc[ct][r]);
        }
      }
    }
  }
}

extern "C" void kernel_launch(void* const* d_in, const int* in_sizes, int n_in,
                              void* d_out, int out_size, void* d_ws, size_t ws_size,
                              hipStream_t stream)
{
  (void)in_sizes; (void)n_in; (void)out_size;
  const void* prot = d_in[0];
  const void* mol  = d_in[1];
  const int* pb    = (const int*)d_in[2];
  const int* mb    = (const int*)d_in[3];
  const void* Wq   = d_in[4];
  const void* bq   = d_in[5];
  const void* Wk   = d_in[6];
  const void* bk   = d_in[7];
  const void* Wv   = d_in[8];
  const void* bv   = d_in[9];

  const size_t qb = (size_t)NPROT * HID * 2;
  const size_t kb = (size_t)NMOL * HID * 2;
  const size_t need = 1024 + qb + kb + kb;
  if (ws_size < need) return;   // diagnosable signature: absmax == max|ref|

  char* ws = (char*)d_ws;
  int* rg  = (int*)ws;                      // 1024 B (rg[128] = f32 flag)
  u16* Q   = (u16*)(ws + 1024);
  u16* K   = (u16*)(ws + 1024 + qb);
  u16* Vt  = (u16*)(ws + 1024 + qb + kb);

  ranges_kernel<<<dim3(1), dim3(256), 0, stream>>>(pb, mb, (const u32*)Wq, rg);
  proj_kernel<<<dim3(192, 4, 3), dim3(256), 0, stream>>>(
      prot, mol, Wq, bq, Wk, bk, Wv, bv, rg, Q, K, Vt);
  attn_kernel<<<dim3(16, NB), dim3(256), 0, stream>>>(rg, Q, K, Vt, d_out);
}

// Round 3
// 441.845 us; speedup vs baseline: 1.2866x; 1.2866x over previous
//
#include <hip/hip_runtime.h>

#define NPROT 12288
#define NMOL  6144
#define HID   256
#define NB    32

// bf16 scratch layout (u16-element offsets, base = ws + 1024)
#define PROT_O 0
#define MOL_O  3145728
#define WQ_O   4718592
#define WK_O   4784128
#define WV_O   4849664
#define BQ_O   4915200
#define BK_O   4915456
#define BV_O   4915712
#define Q_O    4915968
#define K_O    8061696
#define VT_O   9634560
#define CVT_END 11207424

typedef __attribute__((ext_vector_type(4))) float f32x4;
typedef __attribute__((ext_vector_type(8))) short bf16x8;
typedef unsigned short u16;
typedef unsigned int   u32;

__device__ __forceinline__ float b2f(u16 u){
  union { u32 i; float f; } v; v.i = ((u32)u) << 16; return v.f;
}
__device__ __forceinline__ u16 f2b(float f){
  union { float fl; u32 i; } v; v.fl = f;
  u32 i = v.i;
  return (u16)((i + 0x7FFFu + ((i >> 16) & 1u)) >> 16);  // RNE
}

// ---------------------------------------------------------------------------
// Init: per-batch ranges (parallel over 1024 threads) + dtype probe.
// rg[0..31]=prot start, [32..63]=prot end, [64..95]=mol start, [96..127]=mol end
// rg[128] = 1 if inputs are float32.
// ---------------------------------------------------------------------------
__global__ __launch_bounds__(1024) void init_kernel(
    const int* __restrict__ pb, const int* __restrict__ mb,
    const u32* __restrict__ wq_raw, int* __restrict__ rg){
  int t = threadIdx.x;
  if (t < 132) rg[t] = 0;
  __syncthreads();
  for (int i = t; i < NPROT; i += 1024){
    int b = pb[i];
    if (i == 0 || pb[i-1] != b) rg[b] = i;
    if (i == NPROT-1 || pb[i+1] != b) rg[32+b] = i+1;
  }
  for (int i = t; i < NMOL; i += 1024){
    int b = mb[i];
    if (i == 0 || mb[i-1] != b) rg[64+b] = i;
    if (i == NMOL-1 || mb[i+1] != b) rg[96+b] = i+1;
  }
  if (t == 0){
    // f32 data: low halfwords uniform-random -> ~52% have bf16-exp >= 0x7B;
    // true bf16 U(-1/16,1/16) weights: none.
    int cnt = 0;
    #pragma unroll
    for (int i = 0; i < 64; i++){
      u32 lo = wq_raw[i] & 0xFFFFu;
      if (((lo >> 7) & 0xFFu) >= 0x7Bu) cnt++;
    }
    rg[128] = (cnt >= 16) ? 1 : 0;
  }
}

// ---------------------------------------------------------------------------
// One-time f32 -> bf16 conversion of all inputs into ws (skipped if bf16).
// ---------------------------------------------------------------------------
__global__ __launch_bounds__(256) void convert_kernel(
    const float* __restrict__ prot, const float* __restrict__ mol,
    const float* __restrict__ Wq, const float* __restrict__ Wk,
    const float* __restrict__ Wv, const float* __restrict__ bq,
    const float* __restrict__ bk, const float* __restrict__ bv,
    const int* __restrict__ rg, u16* __restrict__ dst0){
  if (!rg[128]) return;
  const float* src; u16* dst; int n;
  switch (blockIdx.y){
    case 0:  src = prot; dst = dst0 + PROT_O; n = 3145728; break;
    case 1:  src = mol;  dst = dst0 + MOL_O;  n = 1572864; break;
    case 2:  src = Wq;   dst = dst0 + WQ_O;   n = 65536;   break;
    case 3:  src = Wk;   dst = dst0 + WK_O;   n = 65536;   break;
    case 4:  src = Wv;   dst = dst0 + WV_O;   n = 65536;   break;
    case 5:  src = bq;   dst = dst0 + BQ_O;   n = 256;     break;
    case 6:  src = bk;   dst = dst0 + BK_O;   n = 256;     break;
    default: src = bv;   dst = dst0 + BV_O;   n = 256;     break;
  }
  int i4 = blockIdx.x * 256 + threadIdx.x;
  if (i4 * 4 >= n) return;
  f32x4 v = *(const f32x4*)(src + (size_t)i4 * 4);
  ushort4 o;
  o.x = f2b(v[0]); o.y = f2b(v[1]); o.z = f2b(v[2]); o.w = f2b(v[3]);
  *(ushort4*)(dst + (size_t)i4 * 4) = o;
}

// ---------------------------------------------------------------------------
// Projections (pure bf16): out[i][j] = sum_k x[i][k]*W[j][k] + b[j]
// blockIdx.z: 0=Q (prot), 1=K (mol), 2=V (mol, stored transposed as Vt[h][mol])
// Wave computes 16x64 tile. C/D layout: col=lane&15, row=(lane>>4)*4+reg.
// ---------------------------------------------------------------------------
__global__ __launch_bounds__(256) void proj_kernel(
    const void* __restrict__ prot0, const void* __restrict__ mol0,
    const void* __restrict__ Wq0, const void* __restrict__ bq0,
    const void* __restrict__ Wk0, const void* __restrict__ bk0,
    const void* __restrict__ Wv0, const void* __restrict__ bv0,
    const int* __restrict__ rg, const u16* __restrict__ cvt,
    u16* __restrict__ Q, u16* __restrict__ K, u16* __restrict__ Vt)
{
  __shared__ u16 tlds[4][64][18];
  int f32f = rg[128];
  int proj = blockIdx.z;
  const u16 *X, *W, *B;
  int nrows;
  if (proj == 0){
    X = f32f ? cvt + PROT_O : (const u16*)prot0;
    W = f32f ? cvt + WQ_O   : (const u16*)Wq0;
    B = f32f ? cvt + BQ_O   : (const u16*)bq0;
    nrows = NPROT;
  } else if (proj == 1){
    X = f32f ? cvt + MOL_O  : (const u16*)mol0;
    W = f32f ? cvt + WK_O   : (const u16*)Wk0;
    B = f32f ? cvt + BK_O   : (const u16*)bk0;
    nrows = NMOL;
  } else {
    X = f32f ? cvt + MOL_O  : (const u16*)mol0;
    W = f32f ? cvt + WV_O   : (const u16*)Wv0;
    B = f32f ? cvt + BV_O   : (const u16*)bv0;
    nrows = NMOL;
  }
  if ((int)blockIdx.x * 64 >= nrows) return;

  int wave = threadIdx.x >> 6, lane = threadIdx.x & 63;
  int m = lane & 15, q = lane >> 4;
  int rowbase = blockIdx.x * 64 + wave * 16;
  int colbase = blockIdx.y * 64;

  const u16* arow = X + (size_t)(rowbase + m) * HID;
  f32x4 acc[4] = {};
  for (int k0 = 0; k0 < HID; k0 += 32){
    bf16x8 a = *(const bf16x8*)(arow + k0 + q*8);
    #pragma unroll
    for (int ct = 0; ct < 4; ct++){
      bf16x8 b = *(const bf16x8*)(W + (size_t)(colbase + ct*16 + m) * HID + k0 + q*8);
      acc[ct] = __builtin_amdgcn_mfma_f32_16x16x32_bf16(a, b, acc[ct], 0, 0, 0);
    }
  }

  if (proj < 2){
    u16* O = (proj == 0) ? Q : K;
    #pragma unroll
    for (int ct = 0; ct < 4; ct++){
      int col = colbase + ct*16 + m;
      float bb = b2f(B[col]);
      #pragma unroll
      for (int r = 0; r < 4; r++){
        int row = rowbase + q*4 + r;
        O[(size_t)row * HID + col] = f2b(acc[ct][r] + bb);
      }
    }
  } else {
    #pragma unroll
    for (int ct = 0; ct < 4; ct++){
      int lc = ct*16 + m;
      float bb = b2f(B[colbase + lc]);
      #pragma unroll
      for (int r = 0; r < 4; r++)
        tlds[wave][lc][q*4 + r] = f2b(acc[ct][r] + bb);
    }
    __syncthreads();
    int col = colbase + lane;
    u32 packed[8];
    #pragma unroll
    for (int i = 0; i < 8; i++){
      u16 lo = tlds[wave][lane][2*i];
      u16 hi = tlds[wave][lane][2*i+1];
      packed[i] = (u32)lo | ((u32)hi << 16);
    }
    u16* dst = Vt + (size_t)col * NMOL + rowbase;
    uint4 v0 = {packed[0], packed[1], packed[2], packed[3]};
    uint4 v1 = {packed[4], packed[5], packed[6], packed[7]};
    *(uint4*)dst = v0;
    *(uint4*)(dst + 8) = v1;
  }
}

// ---------------------------------------------------------------------------
// Attention: one BLOCK (4 waves) per 16-row tile. Waves split the mol range;
// online-softmax partials merged via LDS; P written to attn; O reduced across
// waves via 2-stage LDS reduction. Zero-fill outside the block range fused.
// ---------------------------------------------------------------------------
__global__ __launch_bounds__(256) void attn_kernel(
    const int* __restrict__ rg, const u16* __restrict__ Q, const u16* __restrict__ K,
    const u16* __restrict__ Vt, void* __restrict__ dout)
{
  __shared__ u16 plds[4][16][48];
  __shared__ float mxw[4][16];
  __shared__ float smw[4][16];
  __shared__ float red[2][4096];   // [slot][(ct*4+r)*64 + lane]
  const float scale = 0.0625f;     // 1/sqrt(256)
  int f32f = rg[128];
  int b = blockIdx.y;
  int ps = rg[b], pe = rg[32+b], ms = rg[64+b], me = rg[96+b];
  int Np = pe - ps, Nm = me - ms;
  if (Np <= 0) return;

  int wave = threadIdx.x >> 6, lane = threadIdx.x & 63;
  int m = lane & 15, q = lane >> 4;
  float* outf  = (float*)dout;
  u16*   outh  = (u16*)dout;
  float* attnf = outf + (size_t)NPROT * HID;
  u16*   attnh = outh + (size_t)NPROT * HID;
  int ntiles = (Np + 15) >> 4;

  int bs = 0, ce = 0;
  if (Nm > 0){ bs = ms & ~31; ce = bs + ((me - bs + 31) & ~31); }

  for (int tile = blockIdx.x; tile < ntiles; tile += gridDim.x){
    int row0 = ps + tile * 16;

    // ---- zero-fill cols outside [bs, ce), 4 waves split columns ----
    if (f32f){
      for (int cs = wave*64; cs < NMOL; cs += 256){
        int col = cs + m*4;
        if (col < bs || col >= ce){
          f32x4 z = {0.f, 0.f, 0.f, 0.f};
          #pragma unroll
          for (int rr = 0; rr < 4; rr++){
            int row = row0 + q*4 + rr;
            if (row < pe) *(f32x4*)(attnf + (size_t)row * NMOL + col) = z;
          }
        }
      }
    } else {
      for (int cs = wave*128; cs < NMOL; cs += 512){
        int col = cs + m*8;
        if (col < bs || col >= ce){
          uint4 z = {0u, 0u, 0u, 0u};
          #pragma unroll
          for (int rr = 0; rr < 4; rr++){
            int row = row0 + q*4 + rr;
            if (row < pe) *(uint4*)(attnh + (size_t)row * NMOL + col) = z;
          }
        }
      }
    }

    int qr = min(row0 + m, NPROT - 1);
    const u16* qrow = Q + (size_t)qr * HID;
    bf16x8 qf[8];
    #pragma unroll
    for (int kk = 0; kk < 8; kk++)
      qf[kk] = *(const bf16x8*)(qrow + kk*32 + q*8);

    if (Nm > 0){
      // ---- phase A: per-wave online max+sum over its column strip ----
      float mx[4] = {-1e30f, -1e30f, -1e30f, -1e30f};
      float sm[4] = {0.f, 0.f, 0.f, 0.f};
      for (int j0 = bs + wave*16; j0 < me; j0 += 64){
        int col = j0 + m;
        bool valid = (col >= ms) && (col < me);
        const u16* krow = K + (size_t)min(col, NMOL-1) * HID;
        f32x4 s = {0.f, 0.f, 0.f, 0.f};
        #pragma unroll
        for (int kk = 0; kk < 8; kk++){
          bf16x8 kb = *(const bf16x8*)(krow + kk*32 + q*8);
          s = __builtin_amdgcn_mfma_f32_16x16x32_bf16(qf[kk], kb, s, 0, 0, 0);
        }
        float sv[4], cm[4];
        #pragma unroll
        for (int r = 0; r < 4; r++){
          sv[r] = valid ? s[r] * scale : -1e30f;
          cm[r] = sv[r];
        }
        #pragma unroll
        for (int d = 1; d < 16; d <<= 1)
          #pragma unroll
          for (int r = 0; r < 4; r++)
            cm[r] = fmaxf(cm[r], __shfl_xor(cm[r], d, 16));
        float e[4];
        #pragma unroll
        for (int r = 0; r < 4; r++){
          float mn = fmaxf(mx[r], cm[r]);
          float corr = __expf(mx[r] - mn);
          e[r] = __expf(sv[r] - mn);
          mx[r] = mn;
          sm[r] = sm[r] * corr;
        }
        #pragma unroll
        for (int d = 1; d < 16; d <<= 1)
          #pragma unroll
          for (int r = 0; r < 4; r++)
            e[r] += __shfl_xor(e[r], d, 16);
        #pragma unroll
        for (int r = 0; r < 4; r++) sm[r] += e[r];
      }
      if (m == 0){
        #pragma unroll
        for (int r = 0; r < 4; r++){
          mxw[wave][q*4 + r] = mx[r];
          smw[wave][q*4 + r] = sm[r];
        }
      }
      __syncthreads();

      // ---- merge online-softmax state across waves ----
      float gmx[4], ginv[4];
      #pragma unroll
      for (int r = 0; r < 4; r++){
        int row = q*4 + r;
        float M = mxw[0][row];
        #pragma unroll
        for (int w = 1; w < 4; w++) M = fmaxf(M, mxw[w][row]);
        float S = 0.f;
        #pragma unroll
        for (int w = 0; w < 4; w++) S += smw[w][row] * __expf(mxw[w][row] - M);
        gmx[r] = M;
        ginv[r] = (S > 0.f) ? (1.f / S) : 0.f;
      }

      // ---- phase B: P stores + PV on this wave's strip ----
      f32x4 oacc[16] = {};
      for (int j0 = bs + wave*32; j0 < ce; j0 += 128){
        #pragma unroll
        for (int sub = 0; sub < 2; sub++){
          int col = j0 + sub*16 + m;
          bool valid = (col >= ms) && (col < me);
          const u16* krow = K + (size_t)col * HID;   // col < ce <= NMOL
          f32x4 s = {0.f, 0.f, 0.f, 0.f};
          #pragma unroll
          for (int kk = 0; kk < 8; kk++){
            bf16x8 kb = *(const bf16x8*)(krow + kk*32 + q*8);
            s = __builtin_amdgcn_mfma_f32_16x16x32_bf16(qf[kk], kb, s, 0, 0, 0);
          }
          #pragma unroll
          for (int r = 0; r < 4; r++){
            float pv = valid ? __expf(s[r]*scale - gmx[r]) * ginv[r] : 0.f;
            u16 pb16 = f2b(pv);
            plds[wave][q*4 + r][sub*16 + m] = pb16;
            int row = row0 + q*4 + r;
            if (row < pe){
              if (f32f) attnf[(size_t)row * NMOL + col] = pv;
              else      attnh[(size_t)row * NMOL + col] = pb16;
            }
          }
        }
        bf16x8 a = *(const bf16x8*)(&plds[wave][m][q*8]);
        int kbase = j0 + q*8;
        #pragma unroll
        for (int ct = 0; ct < 16; ct++){
          bf16x8 vb = *(const bf16x8*)(Vt + (size_t)(ct*16 + m) * NMOL + kbase);
          oacc[ct] = __builtin_amdgcn_mfma_f32_16x16x32_bf16(a, vb, oacc[ct], 0, 0, 0);
        }
      }
      __syncthreads();

      // ---- 2-stage O reduction across waves ----
      if (wave == 1 || wave == 3){
        float* dst = red[(wave - 1) >> 1];
        #pragma unroll
        for (int ct = 0; ct < 16; ct++)
          #pragma unroll
          for (int r = 0; r < 4; r++)
            dst[(ct*4 + r)*64 + lane] = oacc[ct][r];
      }
      __syncthreads();
      if (wave == 0 || wave == 2){
        const float* src = red[wave >> 1];
        #pragma unroll
        for (int ct = 0; ct < 16; ct++)
          #pragma unroll
          for (int r = 0; r < 4; r++)
            oacc[ct][r] += src[(ct*4 + r)*64 + lane];
      }
      __syncthreads();
      if (wave == 2){
        #pragma unroll
        for (int ct = 0; ct < 16; ct++)
          #pragma unroll
          for (int r = 0; r < 4; r++)
            red[0][(ct*4 + r)*64 + lane] = oacc[ct][r];
      }
      __syncthreads();
      if (wave == 0){
        #pragma unroll
        for (int ct = 0; ct < 16; ct++){
          int colh = ct*16 + m;
          #pragma unroll
          for (int r = 0; r < 4; r++){
            float o = oacc[ct][r] + red[0][(ct*4 + r)*64 + lane];
            int row = row0 + q*4 + r;
            if (row < pe){
              if (f32f) outf[(size_t)row * HID + colh] = o;
              else      outh[(size_t)row * HID + colh] = f2b(o);
            }
          }
        }
      }
    } else {
      // no valid keys for this batch: O rows are zeros
      if (wave == 0){
        #pragma unroll
        for (int ct = 0; ct < 16; ct++){
          int colh = ct*16 + m;
          #pragma unroll
          for (int r = 0; r < 4; r++){
            int row = row0 + q*4 + r;
            if (row < pe){
              if (f32f) outf[(size_t)row * HID + colh] = 0.f;
              else      outh[(size_t)row * HID + colh] = 0;
            }
          }
        }
      }
    }
    __syncthreads();   // protect mxw/smw/red/plds reuse across tile iterations
  }
}

extern "C" void kernel_launch(void* const* d_in, const int* in_sizes, int n_in,
                              void* d_out, int out_size, void* d_ws, size_t ws_size,
                              hipStream_t stream)
{
  (void)in_sizes; (void)n_in; (void)out_size;
  const void* prot = d_in[0];
  const void* mol  = d_in[1];
  const int* pb    = (const int*)d_in[2];
  const int* mb    = (const int*)d_in[3];
  const void* Wq   = d_in[4];
  const void* bq   = d_in[5];
  const void* Wk   = d_in[6];
  const void* bk   = d_in[7];
  const void* Wv   = d_in[8];
  const void* bv   = d_in[9];

  const size_t need = 1024 + (size_t)CVT_END * 2;
  if (ws_size < need) return;

  char* ws = (char*)d_ws;
  int* rg  = (int*)ws;
  u16* cvt = (u16*)(ws + 1024);
  u16* Qp  = cvt + Q_O;
  u16* Kp  = cvt + K_O;
  u16* Vtp = cvt + VT_O;

  init_kernel<<<dim3(1), dim3(1024), 0, stream>>>(pb, mb, (const u32*)Wq, rg);
  convert_kernel<<<dim3(3072, 8), dim3(256), 0, stream>>>(
      (const float*)prot, (const float*)mol, (const float*)Wq, (const float*)Wk,
      (const float*)Wv, (const float*)bq, (const float*)bk, (const float*)bv, rg, cvt);
  proj_kernel<<<dim3(192, 4, 3), dim3(256), 0, stream>>>(
      prot, mol, Wq, bq, Wk, bk, Wv, bv, rg, cvt, Qp, Kp, Vtp);
  attn_kernel<<<dim3(32, NB), dim3(256), 0, stream>>>(rg, Qp, Kp, Vtp, d_out);
}

// Round 5
// 417.670 us; speedup vs baseline: 1.3610x; 1.0579x over previous
//
#include <hip/hip_runtime.h>

#define NPROT 12288
#define NMOL  6144
#define HID   256
#define NB    32

// bf16 scratch layout (u16-element offsets, base = ws + 1024)
#define PROT_O 0
#define MOL_O  3145728
#define WQ_O   4718592
#define WK_O   4784128
#define WV_O   4849664
#define BQ_O   4915200
#define BK_O   4915456
#define BV_O   4915712
#define Q_O    4915968
#define K_O    8061696
#define VT_O   9634560
#define END_O  11207424

typedef __attribute__((ext_vector_type(4))) float f32x4;
typedef __attribute__((ext_vector_type(8))) short bf16x8;
typedef unsigned short u16;
typedef unsigned int   u32;

__device__ __forceinline__ float b2f(u16 u){
  union { u32 i; float f; } v; v.i = ((u32)u) << 16; return v.f;
}
__device__ __forceinline__ u16 f2b(float f){
  union { float fl; u32 i; } v; v.fl = f;
  u32 i = v.i;
  return (u16)((i + 0x7FFFu + ((i >> 16) & 1u)) >> 16);  // RNE
}

// ---------------------------------------------------------------------------
// Convert: f32 -> bf16 for all inputs into ws (1D right-sized grid, 4801
// blocks x 256 thr, one quad each). Block 0 wave 0 additionally computes the
// per-batch ranges via 64 binary searches over the sorted batch arrays:
// rg[b]=prot start, rg[32+b]=prot end, rg[64+b]=mol start, rg[96+b]=mol end.
// ---------------------------------------------------------------------------
__global__ __launch_bounds__(256) void convert_kernel(
    const float* __restrict__ prot, const float* __restrict__ mol,
    const float* __restrict__ Wq, const float* __restrict__ Wk,
    const float* __restrict__ Wv, const float* __restrict__ bq,
    const float* __restrict__ bk, const float* __restrict__ bv,
    const int* __restrict__ pb, const int* __restrict__ mb,
    int* __restrict__ rg, u16* __restrict__ cvt)
{
  int g = blockIdx.x * 256 + threadIdx.x;   // quad index
  const float* src = nullptr; u16* dst = nullptr; int off = 0;
  if      (g < 786432)  { src = prot; dst = cvt + PROT_O; off = g; }
  else if (g < 1179648) { src = mol;  dst = cvt + MOL_O;  off = g - 786432; }
  else if (g < 1196032) { src = Wq;   dst = cvt + WQ_O;   off = g - 1179648; }
  else if (g < 1212416) { src = Wk;   dst = cvt + WK_O;   off = g - 1196032; }
  else if (g < 1228800) { src = Wv;   dst = cvt + WV_O;   off = g - 1212416; }
  else if (g < 1228864) { src = bq;   dst = cvt + BQ_O;   off = g - 1228800; }
  else if (g < 1228928) { src = bk;   dst = cvt + BK_O;   off = g - 1228864; }
  else if (g < 1228992) { src = bv;   dst = cvt + BV_O;   off = g - 1228928; }
  if (src){
    f32x4 v = *(const f32x4*)(src + (size_t)off * 4);
    ushort4 o;
    o.x = f2b(v[0]); o.y = f2b(v[1]); o.z = f2b(v[2]); o.w = f2b(v[3]);
    *(ushort4*)(dst + (size_t)off * 4) = o;
  }

  if (blockIdx.x == 0 && threadIdx.x < 64){
    int t = threadIdx.x;
    const int* arr = (t < 32) ? pb : mb;
    int n          = (t < 32) ? NPROT : NMOL;
    int target     = (t & 31) + 1;
    int lo = 0, hi = n;
    while (lo < hi){                // lower_bound(target): first i arr[i]>=target
      int mid = (lo + hi) >> 1;
      if (arr[mid] < target) lo = mid + 1; else hi = mid;
    }
    int end = lo;
    int prev = __shfl(end, t - 1);  // end of batch b-1 == start of batch b
    int start = ((t & 31) == 0) ? 0 : prev;
    int b = t & 31;
    if (t < 32){ rg[b] = start; rg[32 + b] = end; }
    else       { rg[64 + b] = start; rg[96 + b] = end; }
  }
}

// ---------------------------------------------------------------------------
// Projections (bf16 in ws): out[i][j] = sum_k x[i][k]*W[j][k] + b[j]
// grid (384, 4): x<192 -> Q rows, x<288 -> K rows, else V rows (V stored
// transposed as Vt[h][mol]). Wave computes a 16x64 tile.
// C/D layout: col = lane&15, row = (lane>>4)*4 + reg.
// ---------------------------------------------------------------------------
__global__ __launch_bounds__(256) void proj_kernel(
    const u16* __restrict__ cvt,
    u16* __restrict__ Q, u16* __restrict__ K, u16* __restrict__ Vt)
{
  __shared__ u16 tlds[4][64][18];
  int x = blockIdx.x;
  int proj, rowblk;
  if      (x < 192){ proj = 0; rowblk = x; }
  else if (x < 288){ proj = 1; rowblk = x - 192; }
  else             { proj = 2; rowblk = x - 288; }
  const u16 *X, *W, *B;
  if (proj == 0){ X = cvt + PROT_O; W = cvt + WQ_O; B = cvt + BQ_O; }
  else if (proj == 1){ X = cvt + MOL_O; W = cvt + WK_O; B = cvt + BK_O; }
  else { X = cvt + MOL_O; W = cvt + WV_O; B = cvt + BV_O; }

  int wave = threadIdx.x >> 6, lane = threadIdx.x & 63;
  int m = lane & 15, q = lane >> 4;
  int rowbase = rowblk * 64 + wave * 16;
  int colbase = blockIdx.y * 64;

  const u16* arow = X + (size_t)(rowbase + m) * HID;
  f32x4 acc[4] = {};
  for (int k0 = 0; k0 < HID; k0 += 32){
    bf16x8 a = *(const bf16x8*)(arow + k0 + q*8);
    #pragma unroll
    for (int ct = 0; ct < 4; ct++){
      bf16x8 b = *(const bf16x8*)(W + (size_t)(colbase + ct*16 + m) * HID + k0 + q*8);
      acc[ct] = __builtin_amdgcn_mfma_f32_16x16x32_bf16(a, b, acc[ct], 0, 0, 0);
    }
  }

  if (proj < 2){
    u16* O = (proj == 0) ? Q : K;
    #pragma unroll
    for (int ct = 0; ct < 4; ct++){
      int col = colbase + ct*16 + m;
      float bb = b2f(B[col]);
      #pragma unroll
      for (int r = 0; r < 4; r++){
        int row = rowbase + q*4 + r;
        O[(size_t)row * HID + col] = f2b(acc[ct][r] + bb);
      }
    }
  } else {
    #pragma unroll
    for (int ct = 0; ct < 4; ct++){
      int lc = ct*16 + m;
      float bb = b2f(B[colbase + lc]);
      #pragma unroll
      for (int r = 0; r < 4; r++)
        tlds[wave][lc][q*4 + r] = f2b(acc[ct][r] + bb);
    }
    __syncthreads();
    int col = colbase + lane;
    u32 packed[8];
    #pragma unroll
    for (int i = 0; i < 8; i++){
      u16 lo = tlds[wave][lane][2*i];
      u16 hi = tlds[wave][lane][2*i+1];
      packed[i] = (u32)lo | ((u32)hi << 16);
    }
    u16* dst = Vt + (size_t)col * NMOL + rowbase;
    uint4 v0 = {packed[0], packed[1], packed[2], packed[3]};
    uint4 v1 = {packed[4], packed[5], packed[6], packed[7]};
    *(uint4*)dst = v0;
    *(uint4*)(dst + 8) = v1;
  }
}

// ---------------------------------------------------------------------------
// Attention (f32 out): one BLOCK (4 waves) per 16-row tile; waves split the
// mol range; online-softmax state merged via LDS; O reduced across waves.
// Zero-fill of out-of-block attn columns fused. QK^T MFMA split into two
// independent 4-chains for latency.
// ---------------------------------------------------------------------------
__global__ __launch_bounds__(256) void attn_kernel(
    const int* __restrict__ rg, const u16* __restrict__ Q, const u16* __restrict__ K,
    const u16* __restrict__ Vt, float* __restrict__ dout)
{
  __shared__ u16 plds[4][16][48];
  __shared__ float mxw[4][16];
  __shared__ float smw[4][16];
  __shared__ float red[2][4096];
  const float scale = 0.0625f;     // 1/sqrt(256)
  int b = blockIdx.y;
  int ps = rg[b], pe = rg[32+b], ms = rg[64+b], me = rg[96+b];
  int Np = pe - ps, Nm = me - ms;
  if (Np <= 0) return;

  int wave = threadIdx.x >> 6, lane = threadIdx.x & 63;
  int m = lane & 15, q = lane >> 4;
  float* outf  = dout;
  float* attnf = dout + (size_t)NPROT * HID;
  int ntiles = (Np + 15) >> 4;

  int bs = 0, ce = 0;
  if (Nm > 0){ bs = ms & ~31; ce = bs + ((me - bs + 31) & ~31); }

  for (int tile = blockIdx.x; tile < ntiles; tile += gridDim.x){
    int row0 = ps + tile * 16;

    // ---- zero-fill cols outside [bs, ce), 4 waves split columns ----
    for (int cs = wave*64; cs < NMOL; cs += 256){
      int col = cs + m*4;
      if (col < bs || col >= ce){
        f32x4 z = {0.f, 0.f, 0.f, 0.f};
        #pragma unroll
        for (int rr = 0; rr < 4; rr++){
          int row = row0 + q*4 + rr;
          if (row < pe) *(f32x4*)(attnf + (size_t)row * NMOL + col) = z;
        }
      }
    }

    int qr = min(row0 + m, NPROT - 1);
    const u16* qrow = Q + (size_t)qr * HID;
    bf16x8 qf[8];
    #pragma unroll
    for (int kk = 0; kk < 8; kk++)
      qf[kk] = *(const bf16x8*)(qrow + kk*32 + q*8);

    if (Nm > 0){
      // ---- phase A: per-wave online max+sum over its column strip ----
      float mx[4] = {-1e30f, -1e30f, -1e30f, -1e30f};
      float sm[4] = {0.f, 0.f, 0.f, 0.f};
      for (int j0 = bs + wave*16; j0 < me; j0 += 64){
        int col = j0 + m;
        bool valid = (col >= ms) && (col < me);
        const u16* krow = K + (size_t)min(col, NMOL-1) * HID;
        f32x4 s0 = {0.f,0.f,0.f,0.f}, s1 = {0.f,0.f,0.f,0.f};
        #pragma unroll
        for (int kk = 0; kk < 4; kk++){
          bf16x8 kb0 = *(const bf16x8*)(krow + kk*32 + q*8);
          bf16x8 kb1 = *(const bf16x8*)(krow + (kk+4)*32 + q*8);
          s0 = __builtin_amdgcn_mfma_f32_16x16x32_bf16(qf[kk],   kb0, s0, 0, 0, 0);
          s1 = __builtin_amdgcn_mfma_f32_16x16x32_bf16(qf[kk+4], kb1, s1, 0, 0, 0);
        }
        f32x4 s = s0 + s1;
        float sv[4], cm[4];
        #pragma unroll
        for (int r = 0; r < 4; r++){
          sv[r] = valid ? s[r] * scale : -1e30f;
          cm[r] = sv[r];
        }
        #pragma unroll
        for (int d = 1; d < 16; d <<= 1)
          #pragma unroll
          for (int r = 0; r < 4; r++)
            cm[r] = fmaxf(cm[r], __shfl_xor(cm[r], d, 16));
        float e[4];
        #pragma unroll
        for (int r = 0; r < 4; r++){
          float mn = fmaxf(mx[r], cm[r]);
          float corr = __expf(mx[r] - mn);
          e[r] = __expf(sv[r] - mn);
          mx[r] = mn;
          sm[r] = sm[r] * corr;
        }
        #pragma unroll
        for (int d = 1; d < 16; d <<= 1)
          #pragma unroll
          for (int r = 0; r < 4; r++)
            e[r] += __shfl_xor(e[r], d, 16);
        #pragma unroll
        for (int r = 0; r < 4; r++) sm[r] += e[r];
      }
      if (m == 0){
        #pragma unroll
        for (int r = 0; r < 4; r++){
          mxw[wave][q*4 + r] = mx[r];
          smw[wave][q*4 + r] = sm[r];
        }
      }
      __syncthreads();

      float gmx[4], ginv[4];
      #pragma unroll
      for (int r = 0; r < 4; r++){
        int row = q*4 + r;
        float M = mxw[0][row];
        #pragma unroll
        for (int w = 1; w < 4; w++) M = fmaxf(M, mxw[w][row]);
        float S = 0.f;
        #pragma unroll
        for (int w = 0; w < 4; w++) S += smw[w][row] * __expf(mxw[w][row] - M);
        gmx[r] = M;
        ginv[r] = (S > 0.f) ? (1.f / S) : 0.f;
      }

      // ---- phase B: P stores + PV on this wave's strip ----
      f32x4 oacc[16] = {};
      for (int j0 = bs + wave*32; j0 < ce; j0 += 128){
        #pragma unroll
        for (int sub = 0; sub < 2; sub++){
          int col = j0 + sub*16 + m;
          bool valid = (col >= ms) && (col < me);
          const u16* krow = K + (size_t)col * HID;
          f32x4 s0 = {0.f,0.f,0.f,0.f}, s1 = {0.f,0.f,0.f,0.f};
          #pragma unroll
          for (int kk = 0; kk < 4; kk++){
            bf16x8 kb0 = *(const bf16x8*)(krow + kk*32 + q*8);
            bf16x8 kb1 = *(const bf16x8*)(krow + (kk+4)*32 + q*8);
            s0 = __builtin_amdgcn_mfma_f32_16x16x32_bf16(qf[kk],   kb0, s0, 0, 0, 0);
            s1 = __builtin_amdgcn_mfma_f32_16x16x32_bf16(qf[kk+4], kb1, s1, 0, 0, 0);
          }
          f32x4 s = s0 + s1;
          #pragma unroll
          for (int r = 0; r < 4; r++){
            float pv = valid ? __expf(s[r]*scale - gmx[r]) * ginv[r] : 0.f;
            u16 pb16 = f2b(pv);
            plds[wave][q*4 + r][sub*16 + m] = pb16;
            int row = row0 + q*4 + r;
            if (row < pe) attnf[(size_t)row * NMOL + col] = pv;
          }
        }
        bf16x8 a = *(const bf16x8*)(&plds[wave][m][q*8]);
        int kbase = j0 + q*8;
        #pragma unroll
        for (int ct = 0; ct < 16; ct++){
          bf16x8 vb = *(const bf16x8*)(Vt + (size_t)(ct*16 + m) * NMOL + kbase);
          oacc[ct] = __builtin_amdgcn_mfma_f32_16x16x32_bf16(a, vb, oacc[ct], 0, 0, 0);
        }
      }
      __syncthreads();

      // ---- 2-stage O reduction across waves ----
      if (wave == 1 || wave == 3){
        float* dst = red[(wave - 1) >> 1];
        #pragma unroll
        for (int ct = 0; ct < 16; ct++)
          #pragma unroll
          for (int r = 0; r < 4; r++)
            dst[(ct*4 + r)*64 + lane] = oacc[ct][r];
      }
      __syncthreads();
      if (wave == 0 || wave == 2){
        const float* src = red[wave >> 1];
        #pragma unroll
        for (int ct = 0; ct < 16; ct++)
          #pragma unroll
          for (int r = 0; r < 4; r++)
            oacc[ct][r] += src[(ct*4 + r)*64 + lane];
      }
      __syncthreads();
      if (wave == 2){
        #pragma unroll
        for (int ct = 0; ct < 16; ct++)
          #pragma unroll
          for (int r = 0; r < 4; r++)
            red[0][(ct*4 + r)*64 + lane] = oacc[ct][r];
      }
      __syncthreads();
      if (wave == 0){
        #pragma unroll
        for (int ct = 0; ct < 16; ct++){
          int colh = ct*16 + m;
          #pragma unroll
          for (int r = 0; r < 4; r++){
            float o = oacc[ct][r] + red[0][(ct*4 + r)*64 + lane];
            int row = row0 + q*4 + r;
            if (row < pe) outf[(size_t)row * HID + colh] = o;
          }
        }
      }
    } else {
      if (wave == 0){
        #pragma unroll
        for (int ct = 0; ct < 16; ct++){
          int colh = ct*16 + m;
          #pragma unroll
          for (int r = 0; r < 4; r++){
            int row = row0 + q*4 + r;
            if (row < pe) outf[(size_t)row * HID + colh] = 0.f;
          }
        }
      }
    }
    __syncthreads();   // protect LDS reuse across tile iterations
  }
}

extern "C" void kernel_launch(void* const* d_in, const int* in_sizes, int n_in,
                              void* d_out, int out_size, void* d_ws, size_t ws_size,
                              hipStream_t stream)
{
  (void)in_sizes; (void)n_in; (void)out_size;
  const float* prot = (const float*)d_in[0];
  const float* mol  = (const float*)d_in[1];
  const int* pb     = (const int*)d_in[2];
  const int* mb     = (const int*)d_in[3];
  const float* Wq   = (const float*)d_in[4];
  const float* bq   = (const float*)d_in[5];
  const float* Wk   = (const float*)d_in[6];
  const float* bk   = (const float*)d_in[7];
  const float* Wv   = (const float*)d_in[8];
  const float* bv   = (const float*)d_in[9];

  const size_t need = 1024 + (size_t)END_O * 2;
  if (ws_size < need) return;

  char* ws = (char*)d_ws;
  int* rg  = (int*)ws;
  u16* cvt = (u16*)(ws + 1024);
  u16* Qp  = cvt + Q_O;
  u16* Kp  = cvt + K_O;
  u16* Vtp = cvt + VT_O;

  convert_kernel<<<dim3(4801), dim3(256), 0, stream>>>(
      prot, mol, Wq, Wk, Wv, bq, bk, bv, pb, mb, rg, cvt);
  proj_kernel<<<dim3(384, 4), dim3(256), 0, stream>>>(cvt, Qp, Kp, Vtp);
  attn_kernel<<<dim3(32, NB), dim3(256), 0, stream>>>(rg, Qp, Kp, Vtp, (float*)d_out);
}